// Round 7
// baseline (1211.072 us; speedup 1.0000x reference)
//
#include <hip/hip_runtime.h>
#include <hip/hip_bf16.h>

#define HD 768
#define N_NODES 16383
#define NLEAF_OFF 8191     // first leaf node index (level d=13 offset)
#define NHF 12582144       // N_NODES * HD
#define TEMP 3.0f

using bf16 = __hip_bfloat16;
typedef __attribute__((ext_vector_type(8))) short bf16x8;
typedef __attribute__((ext_vector_type(4))) float f32x4;

__device__ __forceinline__ float sigm(float x) { return 1.0f / (1.0f + __expf(-x)); }
__device__ __forceinline__ float b2f(bf16 v)   { return __bfloat162float(v); }
__device__ __forceinline__ bf16  f2b(float v)  { return __float2bfloat16(v); }

// async global->LDS, 16B per lane. LDS dest = wave-uniform base + lane*16.
__device__ __forceinline__ void gload16(const void* g, void* l) {
    __builtin_amdgcn_global_load_lds(
        (const __attribute__((address_space(1))) unsigned int*)g,
        (__attribute__((address_space(3))) unsigned int*)l, 16, 0, 0);
}

// ---------------------------------------------------------------------------
// Weight conversion: bf16 B^T matrices, built once per launch.
// Layout is gate-major: BT row index = gate*768 + j, cols = K.
// ---------------------------------------------------------------------------
__global__ __launch_bounds__(256) void convT1_k(
    const float* __restrict__ Ub_iou, const float* __restrict__ Ub_f,
    bf16* __restrict__ BT)
{
    int idx = blockIdx.x * 256 + threadIdx.x;
    if (idx >= 3840 * 1536) return;
    int n = idx / 1536, k = idx - n * 1536;
    int l = (k >= 768);
    int h = k - l * 768;
    float v;
    if (n < 2304) {
        v = Ub_iou[(size_t)k * 2304 + n];
    } else {
        int c2 = n - 2304;
        int kk = c2 / 768, o = c2 - kk * 768;
        v = Ub_f[(((size_t)(kk * 2 + l)) * 768 + h) * 768 + o];
    }
    BT[idx] = f2b(v);
}

__global__ __launch_bounds__(256) void convT2_k(
    const float* __restrict__ Ut_iou, const float* __restrict__ Ut_f,
    bf16* __restrict__ BT)
{
    int idx = blockIdx.x * 256 + threadIdx.x;
    if (idx >= 4608 * 2304) return;
    int n = idx / 2304, k = idx - n * 2304;
    int l = (k >= 768) + (k >= 1536);
    int h = k - l * 768;
    float v;
    if (n < 2304) {
        v = Ut_iou[(size_t)k * 2304 + n];
    } else {
        int c2 = n - 2304;
        int kk = c2 / 768, o = c2 - kk * 768;
        v = Ut_f[(((size_t)(kk * 3 + l)) * 768 + h) * 768 + o];
    }
    BT[idx] = f2b(v);
}

__global__ __launch_bounds__(256) void convW_k(
    const float* __restrict__ W, bf16* __restrict__ WT)
{
    int idx = blockIdx.x * 256 + threadIdx.x;
    if (idx >= 768 * 768) return;
    int n = idx / 768, k = idx - n * 768;
    WT[idx] = f2b(W[(size_t)k * 768 + n]);
}

// Head weights packed: WhT[128][768]; cols 0-1 hl, 2-3 int, 4-67 act, rest 0.
__global__ __launch_bounds__(256) void convH_k(
    const float* __restrict__ hlW, const float* __restrict__ intW,
    const float* __restrict__ actW, bf16* __restrict__ WhT)
{
    int idx = blockIdx.x * 256 + threadIdx.x;
    if (idx >= 128 * 768) return;
    int n = idx / 768, k = idx - n * 768;
    float v = 0.f;
    if (n < 2)       v = hlW[(size_t)k * 2 + n];
    else if (n < 4)  v = intW[(size_t)k * 2 + (n - 2)];
    else if (n < 68) v = actW[(size_t)k * 64 + (n - 4)];
    WhT[idx] = f2b(v);
}

// ---------------------------------------------------------------------------
// FUSED Tree-LSTM level GEMM + cell epilogue.
// NCH=2: pass 1 (5 gates i,o,u,f0,f1; A row r = children of parent off+r,
//        contiguous: Abase + r*1536). NCH=3: pass 2 (6 gates; A row r =
//        [h(r), h(2r+1), h(2r+2)] gathered via per-lane global addresses).
// Block: 256 thr = 4 waves (2x2), tile 64 rows x 64 cols x NG gates.
// LDS: As[64][32], Bs[NG][64][32] staged via global_load_lds dwordx4.
// Epilogue applies the LSTM cell and writes bf16 h (and c for pass 1).
// ---------------------------------------------------------------------------
template <int NCH>
__global__ __launch_bounds__(256) void fmm_k(
    const int* __restrict__ ids,
    const bf16* __restrict__ Abase,
    const bf16* __restrict__ BT,
    const float* __restrict__ Wiou, const float* __restrict__ biou,
    const float* __restrict__ Wf, const float* __restrict__ bfv,
    const bf16* __restrict__ c_all,
    bf16* __restrict__ h_out, bf16* __restrict__ c_out,
    int M, int off)
{
    constexpr int NG = NCH + 3;          // gates
    constexpr int K  = NCH * 768;
    __shared__ short As[64 * 32];
    __shared__ short Bs[NG * 64 * 32];

    int tid  = threadIdx.x;
    int lane = tid & 63;
    int wave = tid >> 6;                 // 0..3
    int wr = wave >> 1, wc = wave & 1;
    int bx = blockIdx.x, by = blockIdx.y;

    f32x4 acc[NG][2][2] = {};

    int sr  = lane >> 2;                 // 0..15
    int sc8 = (lane & 3) * 8;            // 0,8,16,24 (bf16)
    int arow = by * 64 + wave * 16 + sr;
    if (arow > M - 1) arow = M - 1;      // clamp; epilogue skips rows >= M

    // B staging: exactly NG wave-instrs per wave (s = wave + 4t covers 4*NG)
    const bf16* gB[NG];
    short* lB[NG];
#pragma unroll
    for (int t = 0; t < NG; ++t) {
        int s = wave + 4 * t;
        int gb = s >> 2, q = s & 3;
        gB[t] = BT + (size_t)(gb * 768 + bx * 64 + q * 16 + sr) * K + sc8;
        lB[t] = Bs + gb * 2048 + q * 512;
    }
    short* lA = As + wave * 512;
    const bf16* gA1 = Abase + (size_t)arow * 1536 + sc8;   // pass-1 source

    int fr = lane & 15;
    int fk = (lane >> 4) << 3;
    const short* pA = As + (wr * 32 + fr) * 32 + fk;
    const short* pB = Bs + (wc * 32 + fr) * 32 + fk;

    for (int kt = 0; kt < K; kt += 32) {
        if constexpr (NCH == 2) {
            gload16(gA1 + kt, lA);
        } else {
            int ch = (kt >= 768) + (kt >= 1536);
            int node = (ch == 0) ? arow : (2 * arow + ch);
            gload16(Abase + (size_t)node * 768 + (kt - ch * 768) + sc8, lA);
        }
#pragma unroll
        for (int t = 0; t < NG; ++t) gload16(gB[t] + kt, lB[t]);
        __syncthreads();

        bf16x8 a0 = *(const bf16x8*)pA;
        bf16x8 a1 = *(const bf16x8*)(pA + 512);
#pragma unroll
        for (int g = 0; g < NG; ++g) {
            bf16x8 b0 = *(const bf16x8*)(pB + g * 2048);
            bf16x8 b1 = *(const bf16x8*)(pB + g * 2048 + 512);
            acc[g][0][0] = __builtin_amdgcn_mfma_f32_16x16x32_bf16(a0, b0, acc[g][0][0], 0, 0, 0);
            acc[g][0][1] = __builtin_amdgcn_mfma_f32_16x16x32_bf16(a0, b1, acc[g][0][1], 0, 0, 0);
            acc[g][1][0] = __builtin_amdgcn_mfma_f32_16x16x32_bf16(a1, b0, acc[g][1][0], 0, 0, 0);
            acc[g][1][1] = __builtin_amdgcn_mfma_f32_16x16x32_bf16(a1, b1, acc[g][1][1], 0, 0, 0);
        }
        __syncthreads();
    }

    // ---- fused cell epilogue ----
    int lr4 = (lane >> 4) << 2;
    int c0  = bx * 64 + wc * 32 + fr;
#pragma unroll
    for (int m = 0; m < 2; ++m) {
#pragma unroll
        for (int r = 0; r < 4; ++r) {
            int row = by * 64 + wr * 32 + m * 16 + lr4 + r;
            if (row >= M) continue;
            int g = off + row;
            int id = ids[g];
            const float* wi = Wiou + (size_t)id * 2304;
            const float* wf = Wf + (size_t)id * 768;
#pragma unroll
            for (int n = 0; n < 2; ++n) {
                int j = c0 + n * 16;
                float iv = sigm(acc[0][m][n][r] + wi[j] + biou[j]);
                float ov = sigm(acc[1][m][n][r] + wi[768 + j] + biou[768 + j]);
                float uv = tanhf(acc[2][m][n][r] + wi[1536 + j] + biou[1536 + j]);
                float xf = wf[j] + bfv[j];
                float cv;
                if constexpr (NCH == 2) {
                    float f0 = sigm(acc[3][m][n][r] + xf);
                    float f1 = sigm(acc[4][m][n][r] + xf);
                    cv = iv * uv
                       + f0 * b2f(c_all[(size_t)(2 * g + 1) * HD + j])
                       + f1 * b2f(c_all[(size_t)(2 * g + 2) * HD + j]);
                    c_out[(size_t)g * HD + j] = f2b(cv);
                } else {
                    float f0 = sigm(acc[3][m][n][r] + xf);
                    float f1 = sigm(acc[4][m][n][r] + xf);
                    float f2 = sigm(acc[5][m][n][r] + xf);
                    cv = iv * uv
                       + f0 * b2f(c_all[(size_t)g * HD + j])
                       + f1 * b2f(c_all[(size_t)(2 * g + 1) * HD + j])
                       + f2 * b2f(c_all[(size_t)(2 * g + 2) * HD + j]);
                }
                h_out[(size_t)g * HD + j] = f2b(ov * tanhf(cv));
            }
        }
    }
}

// ---------------------------------------------------------------------------
// Plain bf16 MFMA GEMM (m97 structure) for FFN + heads.
// C[M x N] = A @ BT^T. 128x128 tile, 4 waves, BK=32, global_load_lds staging.
// EPI 0: fp32 Cf. EPI 1: bias+relu -> bf16 Cb. EPI 2: bias -> bf16 Cb.
// ---------------------------------------------------------------------------
template <int EPI>
__global__ __launch_bounds__(256) void mm_k(
    const bf16* __restrict__ A, const bf16* __restrict__ BT,
    float* __restrict__ Cf, bf16* __restrict__ Cb,
    const float* __restrict__ bias,
    int M, int N, int K)
{
    __shared__ short As[128 * 32];
    __shared__ short Bs[128 * 32];

    int tid  = threadIdx.x;
    int lane = tid & 63;
    int wave = tid >> 6;
    int wr = wave >> 1, wc = wave & 1;
    int bx = blockIdx.x, by = blockIdx.y;

    f32x4 acc[4][4] = {};

    int sr  = lane >> 2;
    int sc8 = (lane & 3) * 8;
    int arow0 = by * 128 + wave * 16 + sr;
    int arow1 = arow0 + 64;
    if (arow0 > M - 1) arow0 = M - 1;
    if (arow1 > M - 1) arow1 = M - 1;
    const bf16* gA0 = A + (size_t)arow0 * K + sc8;
    const bf16* gA1 = A + (size_t)arow1 * K + sc8;
    const bf16* gB0 = BT + (size_t)(bx * 128 + wave * 16 + sr) * K + sc8;
    const bf16* gB1 = BT + (size_t)(bx * 128 + wave * 16 + sr + 64) * K + sc8;
    short* lA0 = As + wave * 512;
    short* lA1 = As + wave * 512 + 2048;
    short* lB0 = Bs + wave * 512;
    short* lB1 = Bs + wave * 512 + 2048;

    int fr = lane & 15;
    int fk = (lane >> 4) << 3;
    const short* pAf = As + (wr * 64 + fr) * 32 + fk;
    const short* pBf = Bs + (wc * 64 + fr) * 32 + fk;

    for (int kt = 0; kt < K; kt += 32) {
        gload16(gA0 + kt, lA0);
        gload16(gA1 + kt, lA1);
        gload16(gB0 + kt, lB0);
        gload16(gB1 + kt, lB1);
        __syncthreads();

        bf16x8 a[4], b[4];
#pragma unroll
        for (int m = 0; m < 4; m++) a[m] = *(const bf16x8*)(pAf + m * 512);
#pragma unroll
        for (int n = 0; n < 4; n++) b[n] = *(const bf16x8*)(pBf + n * 512);
#pragma unroll
        for (int m = 0; m < 4; m++)
#pragma unroll
            for (int n = 0; n < 4; n++)
                acc[m][n] = __builtin_amdgcn_mfma_f32_16x16x32_bf16(
                    a[m], b[n], acc[m][n], 0, 0, 0);
        __syncthreads();
    }

    int rbase = by * 128 + wr * 64 + ((lane >> 4) << 2);
    int cbase = bx * 128 + wc * 64 + fr;
#pragma unroll
    for (int m = 0; m < 4; m++) {
#pragma unroll
        for (int r = 0; r < 4; r++) {
            int row = rbase + m * 16 + r;
            if (row >= M) continue;
#pragma unroll
            for (int n = 0; n < 4; n++) {
                int col = cbase + n * 16;
                float v = acc[m][n][r];
                if constexpr (EPI == 1) {
                    v = fmaxf(v + bias[col], 0.f);
                    Cb[(size_t)row * N + col] = f2b(v);
                } else if constexpr (EPI == 2) {
                    v = v + bias[col];
                    Cb[(size_t)row * N + col] = f2b(v);
                } else {
                    Cf[(size_t)row * N + col] = v;
                }
            }
        }
    }
}

// ---------------------------------------------------------------------------
// Leaves, pass 1
// ---------------------------------------------------------------------------
__global__ __launch_bounds__(256) void leaf1_k(
    const int* __restrict__ ids,
    const float* __restrict__ Wb, const float* __restrict__ bb,
    bf16* __restrict__ h_all, bf16* __restrict__ c_all)
{
    int idx = blockIdx.x * blockDim.x + threadIdx.x;
    if (idx >= 8192 * HD) return;
    int i = idx / HD, j = idx - i * HD;
    int g = NLEAF_OFF + i;
    int id = ids[g];
    const float* w = Wb + (size_t)id * 3 * HD;
    float iv = sigm(w[j] + bb[j]);
    float ov = sigm(w[HD + j] + bb[HD + j]);
    float gv = tanhf(w[2 * HD + j] + bb[2 * HD + j]);
    float c = iv * gv;
    h_all[(size_t)g * HD + j] = f2b(ov * tanhf(c));
    c_all[(size_t)g * HD + j] = f2b(c);
}

// Leaves, pass 2
__global__ __launch_bounds__(256) void leaf2_k(
    const int* __restrict__ ids,
    const float* __restrict__ Wt, const float* __restrict__ bt,
    bf16* __restrict__ h3_all)
{
    int idx = blockIdx.x * blockDim.x + threadIdx.x;
    if (idx >= 8192 * HD) return;
    int i = idx / HD, j = idx - i * HD;
    int g = NLEAF_OFF + i;
    int id = ids[g];
    const float* w = Wt + (size_t)id * 3 * HD;
    float iv = sigm(w[j] + bt[j]);
    float ov = sigm(w[HD + j] + bt[HD + j]);
    float gv = tanhf(w[2 * HD + j] + bt[2 * HD + j]);
    float c = iv * gv;
    h3_all[(size_t)g * HD + j] = f2b(ov * tanhf(c));
}

// ---------------------------------------------------------------------------
// Head softmaxes from precomputed logits L[g][128] (cols 0-1 hl, 2-3 int,
// 4-67 act). One wave per node, 4 nodes per block. fp32 out rows of 68.
// ---------------------------------------------------------------------------
__global__ __launch_bounds__(256) void hsm_k(
    const float* __restrict__ L, const int* __restrict__ mask,
    const float* __restrict__ hlb, const float* __restrict__ intb,
    const float* __restrict__ actb, float* __restrict__ out)
{
    int g = blockIdx.x * 4 + (threadIdx.x >> 6);
    if (g >= N_NODES) return;
    int t = threadIdx.x & 63;
    const float* lr = L + (size_t)g * 128;

    bool on = mask[(size_t)g * 64 + t] > 0;
    float x = (lr[4 + t] + actb[t]) * (1.0f / TEMP);
    float mx = on ? x : -INFINITY;
#pragma unroll
    for (int o = 32; o; o >>= 1) mx = fmaxf(mx, __shfl_xor(mx, o));
    float e = on ? __expf(x - mx) : 0.0f;
    float s = e;
#pragma unroll
    for (int o = 32; o; o >>= 1) s += __shfl_xor(s, o);
    float r = (s > 0.f) ? e / s : (1.0f / 64.0f);
    out[(size_t)g * 68 + 4 + t] = r;

    if (t == 0) {
        float a = (lr[0] + hlb[0]) * (1.0f / TEMP);
        float b = (lr[1] + hlb[1]) * (1.0f / TEMP);
        float m2 = fmaxf(a, b);
        float e0 = __expf(a - m2), e1 = __expf(b - m2);
        out[(size_t)g * 68 + 0] = e0 / (e0 + e1);
        out[(size_t)g * 68 + 1] = e1 / (e0 + e1);
    } else if (t == 1) {
        float a = (lr[2] + intb[0]) * (1.0f / TEMP);
        float b = (lr[3] + intb[1]) * (1.0f / TEMP);
        float m2 = fmaxf(a, b);
        float e0 = __expf(a - m2), e1 = __expf(b - m2);
        out[(size_t)g * 68 + 2] = e0 / (e0 + e1);
        out[(size_t)g * 68 + 3] = e1 / (e0 + e1);
    }
}

// ---------------------------------------------------------------------------
extern "C" void kernel_launch(void* const* d_in, const int* in_sizes, int n_in,
                              void* d_out, int out_size, void* d_ws, size_t ws_size,
                              hipStream_t stream)
{
    const int*   ids     = (const int*)d_in[0];
    const int*   mask    = (const int*)d_in[1];
    const float* Wb_iou  = (const float*)d_in[2];
    const float* Ub_iou  = (const float*)d_in[3];
    const float* bb_iou  = (const float*)d_in[4];
    const float* Wb_f    = (const float*)d_in[5];
    const float* Ub_f    = (const float*)d_in[6];
    const float* bb_f    = (const float*)d_in[7];
    const float* Wt_iou  = (const float*)d_in[8];
    const float* Ut_iou  = (const float*)d_in[9];
    const float* bt_iou  = (const float*)d_in[10];
    const float* Wt_f    = (const float*)d_in[11];
    const float* Ut_f    = (const float*)d_in[12];
    const float* bt_f    = (const float*)d_in[13];
    const float* ffn_W1  = (const float*)d_in[14];
    const float* ffn_b1  = (const float*)d_in[15];
    const float* ffn_W2  = (const float*)d_in[16];
    const float* ffn_b2  = (const float*)d_in[17];
    const float* hl_W    = (const float*)d_in[18];
    const float* hl_b    = (const float*)d_in[19];
    const float* int_W   = (const float*)d_in[20];
    const float* int_b   = (const float*)d_in[21];
    const float* act_W   = (const float*)d_in[22];
    const float* act_b   = (const float*)d_in[23];

    // ---- workspace layout (~111 MB, static) ----
    char* p = (char*)d_ws;
    bf16* h_all  = (bf16*)p; p += (size_t)NHF * 2;
    bf16* c_all  = (bf16*)p; p += (size_t)NHF * 2;
    bf16* h3_all = (bf16*)p; p += (size_t)NHF * 2;
    bf16* BT1 = (bf16*)p; p += (size_t)3840 * 1536 * 2;
    bf16* BT2 = (bf16*)p; p += (size_t)4608 * 2304 * 2;
    bf16* W1T = (bf16*)p; p += (size_t)768 * 768 * 2;
    bf16* W2T = (bf16*)p; p += (size_t)768 * 768 * 2;
    bf16* WhT = (bf16*)p; p += (size_t)128 * 768 * 2;
    bf16* t1  = c_all;                 // FFN hidden aliases dead c
    bf16* h4  = h_all;                 // FFN out aliases dead h
    float* Lg = (float*)h3_all;        // head logits alias dead h3 (8.4 MB)

    // ---- weight conversions (bf16 B^T, gate-major) ----
    convT1_k<<<(3840 * 1536 + 255) / 256, 256, 0, stream>>>(Ub_iou, Ub_f, BT1);
    convT2_k<<<(4608 * 2304 + 255) / 256, 256, 0, stream>>>(Ut_iou, Ut_f, BT2);
    convW_k<<<(768 * 768 + 255) / 256, 256, 0, stream>>>(ffn_W1, W1T);
    convW_k<<<(768 * 768 + 255) / 256, 256, 0, stream>>>(ffn_W2, W2T);
    convH_k<<<(128 * 768 + 255) / 256, 256, 0, stream>>>(hl_W, int_W, act_W, WhT);

    // ---- pass 1: leaves, then one fused kernel per level ----
    leaf1_k<<<(8192 * HD + 255) / 256, 256, 0, stream>>>(ids, Wb_iou, bb_iou, h_all, c_all);
    for (int d = 12; d >= 0; --d) {
        int n = 1 << d;
        fmm_k<2><<<dim3(12, (n + 63) / 64), 256, 0, stream>>>(
            ids, h_all + (size_t)(2 * n - 1) * HD, BT1,
            Wb_iou, bb_iou, Wb_f, bb_f, c_all, h_all, c_all, n, n - 1);
    }

    // ---- pass 2: all non-leaf nodes in ONE fused launch ----
    fmm_k<3><<<dim3(12, (NLEAF_OFF + 63) / 64), 256, 0, stream>>>(
        ids, h_all, BT2, Wt_iou, bt_iou, Wt_f, bt_f, c_all,
        h3_all, nullptr, NLEAF_OFF, 0);
    leaf2_k<<<(8192 * HD + 255) / 256, 256, 0, stream>>>(ids, Wt_iou, bt_iou, h3_all);

    // ---- FFN (bias/relu fused epilogues, bf16 out) ----
    mm_k<1><<<dim3(6, 128), 256, 0, stream>>>(
        h3_all, W1T, nullptr, t1, ffn_b1, N_NODES, 768, 768);
    mm_k<2><<<dim3(6, 128), 256, 0, stream>>>(
        t1, W2T, nullptr, h4, ffn_b2, N_NODES, 768, 768);

    // ---- heads: logits GEMM (into dead h3 space) + softmax ----
    mm_k<0><<<dim3(1, 128), 256, 0, stream>>>(
        h4, WhT, Lg, nullptr, nullptr, N_NODES, 128, 768);
    hsm_k<<<(N_NODES + 3) / 4, 256, 0, stream>>>(
        Lg, mask, hl_b, int_b, act_b, (float*)d_out);
}

// Round 8
// 1097.775 us; speedup vs baseline: 1.1032x; 1.1032x over previous
//
#include <hip/hip_runtime.h>
#include <hip/hip_bf16.h>

#define HD 768
#define N_NODES 16383
#define NLEAF_OFF 8191     // first leaf node index (level d=13 offset)
#define NHF 12582144       // N_NODES * HD
#define TEMP 3.0f

using bf16 = __hip_bfloat16;
typedef __attribute__((ext_vector_type(8))) short bf16x8;
typedef __attribute__((ext_vector_type(4))) float f32x4;

__device__ __forceinline__ float sigm(float x) { return 1.0f / (1.0f + __expf(-x)); }
__device__ __forceinline__ float b2f(bf16 v)   { return __bfloat162float(v); }
__device__ __forceinline__ bf16  f2b(float v)  { return __float2bfloat16(v); }

// async global->LDS, 16B per lane. LDS dest = wave-uniform base + lane*16.
__device__ __forceinline__ void gload16(const void* g, void* l) {
    __builtin_amdgcn_global_load_lds(
        (const __attribute__((address_space(1))) unsigned int*)g,
        (__attribute__((address_space(3))) unsigned int*)l, 16, 0, 0);
}

// ---------------------------------------------------------------------------
// ONE fused weight-conversion kernel (bf16 B^T, gate-major layouts).
// Ranges: [0,T1) BT1; [T1,T1+T2) BT2; then W1T, W2T, WhT.
// ---------------------------------------------------------------------------
#define T1SZ 5898240      // 3840*1536
#define T2SZ 10616832     // 4608*2304
#define WSZ  589824       // 768*768
#define HSZ  98304        // 128*768
#define CONVTOT (T1SZ + T2SZ + 2*WSZ + HSZ)

__global__ __launch_bounds__(256) void conv_k(
    const float* __restrict__ Ub_iou, const float* __restrict__ Ub_f,
    const float* __restrict__ Ut_iou, const float* __restrict__ Ut_f,
    const float* __restrict__ ffn_W1, const float* __restrict__ ffn_W2,
    const float* __restrict__ hlW, const float* __restrict__ intW,
    const float* __restrict__ actW,
    bf16* __restrict__ BT1, bf16* __restrict__ BT2,
    bf16* __restrict__ W1T, bf16* __restrict__ W2T, bf16* __restrict__ WhT)
{
    int idx = blockIdx.x * 256 + threadIdx.x;
    if (idx >= CONVTOT) return;
    if (idx < T1SZ) {
        int n = idx / 1536, k = idx - n * 1536;
        int l = (k >= 768);
        int h = k - l * 768;
        float v;
        if (n < 2304) v = Ub_iou[(size_t)k * 2304 + n];
        else {
            int c2 = n - 2304;
            int kk = c2 / 768, o = c2 - kk * 768;
            v = Ub_f[(((size_t)(kk * 2 + l)) * 768 + h) * 768 + o];
        }
        BT1[idx] = f2b(v);
    } else if (idx < T1SZ + T2SZ) {
        int i2 = idx - T1SZ;
        int n = i2 / 2304, k = i2 - n * 2304;
        int l = (k >= 768) + (k >= 1536);
        int h = k - l * 768;
        float v;
        if (n < 2304) v = Ut_iou[(size_t)k * 2304 + n];
        else {
            int c2 = n - 2304;
            int kk = c2 / 768, o = c2 - kk * 768;
            v = Ut_f[(((size_t)(kk * 3 + l)) * 768 + h) * 768 + o];
        }
        BT2[i2] = f2b(v);
    } else if (idx < T1SZ + T2SZ + WSZ) {
        int i2 = idx - T1SZ - T2SZ;
        int n = i2 / 768, k = i2 - n * 768;
        W1T[i2] = f2b(ffn_W1[(size_t)k * 768 + n]);
    } else if (idx < T1SZ + T2SZ + 2 * WSZ) {
        int i2 = idx - T1SZ - T2SZ - WSZ;
        int n = i2 / 768, k = i2 - n * 768;
        W2T[i2] = f2b(ffn_W2[(size_t)k * 768 + n]);
    } else {
        int i2 = idx - T1SZ - T2SZ - 2 * WSZ;
        int n = i2 / 768, k = i2 - n * 768;
        float v = 0.f;
        if (n < 2)       v = hlW[(size_t)k * 2 + n];
        else if (n < 4)  v = intW[(size_t)k * 2 + (n - 2)];
        else if (n < 68) v = actW[(size_t)k * 64 + (n - 4)];
        WhT[i2] = f2b(v);
    }
}

// ---------------------------------------------------------------------------
// Fused leaf kernel: pass-1 h,c AND pass-2 h3 (hc=cc=0 for leaves).
// ---------------------------------------------------------------------------
__global__ __launch_bounds__(256) void leaf_k(
    const int* __restrict__ ids,
    const float* __restrict__ Wb, const float* __restrict__ bb,
    const float* __restrict__ Wt, const float* __restrict__ bt,
    bf16* __restrict__ h_all, bf16* __restrict__ c_all, bf16* __restrict__ h3_all)
{
    int idx = blockIdx.x * blockDim.x + threadIdx.x;
    if (idx >= 8192 * HD) return;
    int i = idx / HD, j = idx - i * HD;
    int g = NLEAF_OFF + i;
    int id = ids[g];
    const float* w = Wb + (size_t)id * 3 * HD;
    float iv = sigm(w[j] + bb[j]);
    float ov = sigm(w[HD + j] + bb[HD + j]);
    float gv = tanhf(w[2 * HD + j] + bb[2 * HD + j]);
    float c = iv * gv;
    h_all[(size_t)g * HD + j] = f2b(ov * tanhf(c));
    c_all[(size_t)g * HD + j] = f2b(c);

    const float* w2 = Wt + (size_t)id * 3 * HD;
    float iv2 = sigm(w2[j] + bt[j]);
    float ov2 = sigm(w2[HD + j] + bt[HD + j]);
    float gv2 = tanhf(w2[2 * HD + j] + bt[2 * HD + j]);
    float c2 = iv2 * gv2;
    h3_all[(size_t)g * HD + j] = f2b(ov2 * tanhf(c2));
}

// ---------------------------------------------------------------------------
// bf16 MFMA GEMM (m97 structure): C[M x N] = A @ BT^T. 128x128 tile, 4 waves,
// BK=32, linear LDS, global_load_lds staging. OOB A rows clamp to M-1.
// GATHER=1 (pass 2): A row r = [h(r), h(2r+1), h(2r+2)] via per-lane sources.
// EPI 0: fp32 Cf. EPI 1: bias+relu bf16. EPI 2: bias bf16. EPI 3: plain bf16.
// ---------------------------------------------------------------------------
template <int EPI, int GATHER>
__global__ __launch_bounds__(256) void mm_k(
    const bf16* __restrict__ A, const bf16* __restrict__ BT,
    float* __restrict__ Cf, bf16* __restrict__ Cb,
    const float* __restrict__ bias,
    int M, int N, int K)
{
    __shared__ short As[128 * 32];
    __shared__ short Bs[128 * 32];

    int tid  = threadIdx.x;
    int lane = tid & 63;
    int wave = tid >> 6;
    int wr = wave >> 1, wc = wave & 1;
    int bx = blockIdx.x, by = blockIdx.y;

    f32x4 acc[4][4] = {};

    int sr  = lane >> 2;
    int sc8 = (lane & 3) * 8;
    int arow0 = by * 128 + wave * 16 + sr;
    int arow1 = arow0 + 64;
    if (arow0 > M - 1) arow0 = M - 1;
    if (arow1 > M - 1) arow1 = M - 1;
    const bf16* gA0 = A + (size_t)arow0 * K + sc8;
    const bf16* gA1 = A + (size_t)arow1 * K + sc8;
    const bf16* gB0 = BT + (size_t)(bx * 128 + wave * 16 + sr) * K + sc8;
    const bf16* gB1 = BT + (size_t)(bx * 128 + wave * 16 + sr + 64) * K + sc8;
    short* lA0 = As + wave * 512;
    short* lA1 = As + wave * 512 + 2048;
    short* lB0 = Bs + wave * 512;
    short* lB1 = Bs + wave * 512 + 2048;

    int fr = lane & 15;
    int fk = (lane >> 4) << 3;
    const short* pAf = As + (wr * 64 + fr) * 32 + fk;
    const short* pBf = Bs + (wc * 64 + fr) * 32 + fk;

    for (int kt = 0; kt < K; kt += 32) {
        if constexpr (GATHER) {
            int ch = (kt >= 768) + (kt >= 1536);
            int col = kt - ch * 768 + sc8;
            int n0 = (ch == 0) ? arow0 : (2 * arow0 + ch);
            int n1 = (ch == 0) ? arow1 : (2 * arow1 + ch);
            gload16(A + (size_t)n0 * HD + col, lA0);
            gload16(A + (size_t)n1 * HD + col, lA1);
        } else {
            gload16(gA0 + kt, lA0);
            gload16(gA1 + kt, lA1);
        }
        gload16(gB0 + kt, lB0);
        gload16(gB1 + kt, lB1);
        __syncthreads();

        bf16x8 a[4], b[4];
#pragma unroll
        for (int m = 0; m < 4; m++) a[m] = *(const bf16x8*)(pAf + m * 512);
#pragma unroll
        for (int n = 0; n < 4; n++) b[n] = *(const bf16x8*)(pBf + n * 512);
#pragma unroll
        for (int m = 0; m < 4; m++)
#pragma unroll
            for (int n = 0; n < 4; n++)
                acc[m][n] = __builtin_amdgcn_mfma_f32_16x16x32_bf16(
                    a[m], b[n], acc[m][n], 0, 0, 0);
        __syncthreads();
    }

    int rbase = by * 128 + wr * 64 + ((lane >> 4) << 2);
    int cbase = bx * 128 + wc * 64 + fr;
#pragma unroll
    for (int m = 0; m < 4; m++) {
#pragma unroll
        for (int r = 0; r < 4; r++) {
            int row = rbase + m * 16 + r;
            if (row >= M) continue;
#pragma unroll
            for (int n = 0; n < 4; n++) {
                int col = cbase + n * 16;
                float v = acc[m][n][r];
                if constexpr (EPI == 1) {
                    v = fmaxf(v + bias[col], 0.f);
                    Cb[(size_t)row * N + col] = f2b(v);
                } else if constexpr (EPI == 2) {
                    v = v + bias[col];
                    Cb[(size_t)row * N + col] = f2b(v);
                } else if constexpr (EPI == 3) {
                    Cb[(size_t)row * N + col] = f2b(v);
                } else {
                    Cf[(size_t)row * N + col] = v;
                }
            }
        }
    }
}

// ---------------------------------------------------------------------------
// FUSED small-level kernel (pass 1, n < 512). 64-row x 64-col x 5-gate tile.
// ---------------------------------------------------------------------------
__global__ __launch_bounds__(256) void fmm_k(
    const int* __restrict__ ids,
    const bf16* __restrict__ Abase,
    const bf16* __restrict__ BT,
    const float* __restrict__ Wiou, const float* __restrict__ biou,
    const float* __restrict__ Wf, const float* __restrict__ bfv,
    const bf16* __restrict__ c_all,
    bf16* __restrict__ h_out, bf16* __restrict__ c_out,
    int M, int off)
{
    constexpr int NG = 5;
    constexpr int K  = 1536;
    __shared__ short As[64 * 32];
    __shared__ short Bs[NG * 64 * 32];

    int tid  = threadIdx.x;
    int lane = tid & 63;
    int wave = tid >> 6;
    int wr = wave >> 1, wc = wave & 1;
    int bx = blockIdx.x, by = blockIdx.y;

    f32x4 acc[NG][2][2] = {};

    int sr  = lane >> 2;
    int sc8 = (lane & 3) * 8;
    int arow = by * 64 + wave * 16 + sr;
    if (arow > M - 1) arow = M - 1;

    const bf16* gB[NG];
    short* lB[NG];
#pragma unroll
    for (int t = 0; t < NG; ++t) {
        int s = wave + 4 * t;
        int gb = s >> 2, q = s & 3;
        gB[t] = BT + (size_t)(gb * 768 + bx * 64 + q * 16 + sr) * K + sc8;
        lB[t] = Bs + gb * 2048 + q * 512;
    }
    short* lA = As + wave * 512;
    const bf16* gA1 = Abase + (size_t)arow * 1536 + sc8;

    int fr = lane & 15;
    int fk = (lane >> 4) << 3;
    const short* pA = As + (wr * 32 + fr) * 32 + fk;
    const short* pB = Bs + (wc * 32 + fr) * 32 + fk;

    for (int kt = 0; kt < K; kt += 32) {
        gload16(gA1 + kt, lA);
#pragma unroll
        for (int t = 0; t < NG; ++t) gload16(gB[t] + kt, lB[t]);
        __syncthreads();

        bf16x8 a0 = *(const bf16x8*)pA;
        bf16x8 a1 = *(const bf16x8*)(pA + 512);
#pragma unroll
        for (int g = 0; g < NG; ++g) {
            bf16x8 b0 = *(const bf16x8*)(pB + g * 2048);
            bf16x8 b1 = *(const bf16x8*)(pB + g * 2048 + 512);
            acc[g][0][0] = __builtin_amdgcn_mfma_f32_16x16x32_bf16(a0, b0, acc[g][0][0], 0, 0, 0);
            acc[g][0][1] = __builtin_amdgcn_mfma_f32_16x16x32_bf16(a0, b1, acc[g][0][1], 0, 0, 0);
            acc[g][1][0] = __builtin_amdgcn_mfma_f32_16x16x32_bf16(a1, b0, acc[g][1][0], 0, 0, 0);
            acc[g][1][1] = __builtin_amdgcn_mfma_f32_16x16x32_bf16(a1, b1, acc[g][1][1], 0, 0, 0);
        }
        __syncthreads();
    }

    int lr4 = (lane >> 4) << 2;
    int c0  = bx * 64 + wc * 32 + fr;
#pragma unroll
    for (int m = 0; m < 2; ++m) {
#pragma unroll
        for (int r = 0; r < 4; ++r) {
            int row = by * 64 + wr * 32 + m * 16 + lr4 + r;
            if (row >= M) continue;
            int g = off + row;
            int id = ids[g];
            const float* wi = Wiou + (size_t)id * 2304;
            const float* wf = Wf + (size_t)id * 768;
#pragma unroll
            for (int n = 0; n < 2; ++n) {
                int j = c0 + n * 16;
                float iv = sigm(acc[0][m][n][r] + wi[j] + biou[j]);
                float ov = sigm(acc[1][m][n][r] + wi[768 + j] + biou[768 + j]);
                float uv = tanhf(acc[2][m][n][r] + wi[1536 + j] + biou[1536 + j]);
                float xf = wf[j] + bfv[j];
                float f0 = sigm(acc[3][m][n][r] + xf);
                float f1 = sigm(acc[4][m][n][r] + xf);
                float cv = iv * uv
                         + f0 * b2f(c_all[(size_t)(2 * g + 1) * HD + j])
                         + f1 * b2f(c_all[(size_t)(2 * g + 2) * HD + j]);
                c_out[(size_t)g * HD + j] = f2b(cv);
                h_out[(size_t)g * HD + j] = f2b(ov * tanhf(cv));
            }
        }
    }
}

// ---------------------------------------------------------------------------
// Pass-1 cell: bf16 S(m x 3840) -> bf16 h,c for nodes [offAbs, offAbs+m)
// ---------------------------------------------------------------------------
__global__ __launch_bounds__(256) void cell1_k(
    const int* __restrict__ ids, const bf16* __restrict__ S,
    const float* __restrict__ Wiou, const float* __restrict__ biou,
    const float* __restrict__ Wf, const float* __restrict__ bfv,
    bf16* __restrict__ h_all, bf16* __restrict__ c_all,
    int m, int offAbs)
{
    int idx = blockIdx.x * blockDim.x + threadIdx.x;
    if (idx >= m * HD) return;
    int i = idx / HD, j = idx - i * HD;
    int g = offAbs + i;
    int id = ids[g];
    const bf16* s = S + (size_t)i * 3840;
    const float* w = Wiou + (size_t)id * 2304;
    float iv = sigm(b2f(s[j]) + w[j] + biou[j]);
    float ov = sigm(b2f(s[HD + j]) + w[HD + j] + biou[HD + j]);
    float gv = tanhf(b2f(s[2 * HD + j]) + w[2 * HD + j] + biou[2 * HD + j]);
    float xf = Wf[(size_t)id * HD + j] + bfv[j];
    float f0 = sigm(b2f(s[3 * HD + j]) + xf);
    float f1 = sigm(b2f(s[4 * HD + j]) + xf);
    float c = iv * gv
            + f0 * b2f(c_all[(size_t)(2 * g + 1) * HD + j])
            + f1 * b2f(c_all[(size_t)(2 * g + 2) * HD + j]);
    h_all[(size_t)g * HD + j] = f2b(ov * tanhf(c));
    c_all[(size_t)g * HD + j] = f2b(c);
}

// ---------------------------------------------------------------------------
// Pass-2 cell: bf16 S(m x 4608) -> bf16 h3 for nodes [g0, g0+m)
// ---------------------------------------------------------------------------
__global__ __launch_bounds__(256) void cell2_k(
    const int* __restrict__ ids, const bf16* __restrict__ S,
    const float* __restrict__ Wiou, const float* __restrict__ biou,
    const float* __restrict__ Wf, const float* __restrict__ bfv,
    const bf16* __restrict__ c_all, bf16* __restrict__ h3_all,
    int m, int g0)
{
    int idx = blockIdx.x * blockDim.x + threadIdx.x;
    if (idx >= m * HD) return;
    int i = idx / HD, j = idx - i * HD;
    int g = g0 + i;
    int id = ids[g];
    const bf16* s = S + (size_t)i * 4608;
    const float* w = Wiou + (size_t)id * 2304;
    float iv = sigm(b2f(s[j]) + w[j] + biou[j]);
    float ov = sigm(b2f(s[HD + j]) + w[HD + j] + biou[HD + j]);
    float gv = tanhf(b2f(s[2 * HD + j]) + w[2 * HD + j] + biou[2 * HD + j]);
    float xf = Wf[(size_t)id * HD + j] + bfv[j];
    float f0 = sigm(b2f(s[3 * HD + j]) + xf);
    float f1 = sigm(b2f(s[4 * HD + j]) + xf);
    float f2 = sigm(b2f(s[5 * HD + j]) + xf);
    float c = iv * gv
            + f0 * b2f(c_all[(size_t)g * HD + j])
            + f1 * b2f(c_all[(size_t)(2 * g + 1) * HD + j])
            + f2 * b2f(c_all[(size_t)(2 * g + 2) * HD + j]);
    h3_all[(size_t)g * HD + j] = f2b(ov * tanhf(c));
}

// ---------------------------------------------------------------------------
// Head softmaxes from logits L[g][128] (0-1 hl, 2-3 int, 4-67 act). fp32 out.
// ---------------------------------------------------------------------------
__global__ __launch_bounds__(256) void hsm_k(
    const float* __restrict__ L, const int* __restrict__ mask,
    const float* __restrict__ hlb, const float* __restrict__ intb,
    const float* __restrict__ actb, float* __restrict__ out)
{
    int g = blockIdx.x * 4 + (threadIdx.x >> 6);
    if (g >= N_NODES) return;
    int t = threadIdx.x & 63;
    const float* lr = L + (size_t)g * 128;

    bool on = mask[(size_t)g * 64 + t] > 0;
    float x = (lr[4 + t] + actb[t]) * (1.0f / TEMP);
    float mx = on ? x : -INFINITY;
#pragma unroll
    for (int o = 32; o; o >>= 1) mx = fmaxf(mx, __shfl_xor(mx, o));
    float e = on ? __expf(x - mx) : 0.0f;
    float s = e;
#pragma unroll
    for (int o = 32; o; o >>= 1) s += __shfl_xor(s, o);
    float r = (s > 0.f) ? e / s : (1.0f / 64.0f);
    out[(size_t)g * 68 + 4 + t] = r;

    if (t == 0) {
        float a = (lr[0] + hlb[0]) * (1.0f / TEMP);
        float b = (lr[1] + hlb[1]) * (1.0f / TEMP);
        float m2 = fmaxf(a, b);
        float e0 = __expf(a - m2), e1 = __expf(b - m2);
        out[(size_t)g * 68 + 0] = e0 / (e0 + e1);
        out[(size_t)g * 68 + 1] = e1 / (e0 + e1);
    } else if (t == 1) {
        float a = (lr[2] + intb[0]) * (1.0f / TEMP);
        float b = (lr[3] + intb[1]) * (1.0f / TEMP);
        float m2 = fmaxf(a, b);
        float e0 = __expf(a - m2), e1 = __expf(b - m2);
        out[(size_t)g * 68 + 2] = e0 / (e0 + e1);
        out[(size_t)g * 68 + 3] = e1 / (e0 + e1);
    }
}

// ---------------------------------------------------------------------------
extern "C" void kernel_launch(void* const* d_in, const int* in_sizes, int n_in,
                              void* d_out, int out_size, void* d_ws, size_t ws_size,
                              hipStream_t stream)
{
    const int*   ids     = (const int*)d_in[0];
    const int*   mask    = (const int*)d_in[1];
    const float* Wb_iou  = (const float*)d_in[2];
    const float* Ub_iou  = (const float*)d_in[3];
    const float* bb_iou  = (const float*)d_in[4];
    const float* Wb_f    = (const float*)d_in[5];
    const float* Ub_f    = (const float*)d_in[6];
    const float* bb_f    = (const float*)d_in[7];
    const float* Wt_iou  = (const float*)d_in[8];
    const float* Ut_iou  = (const float*)d_in[9];
    const float* bt_iou  = (const float*)d_in[10];
    const float* Wt_f    = (const float*)d_in[11];
    const float* Ut_f    = (const float*)d_in[12];
    const float* bt_f    = (const float*)d_in[13];
    const float* ffn_W1  = (const float*)d_in[14];
    const float* ffn_b1  = (const float*)d_in[15];
    const float* ffn_W2  = (const float*)d_in[16];
    const float* ffn_b2  = (const float*)d_in[17];
    const float* hl_W    = (const float*)d_in[18];
    const float* hl_b    = (const float*)d_in[19];
    const float* int_W   = (const float*)d_in[20];
    const float* int_b   = (const float*)d_in[21];
    const float* act_W   = (const float*)d_in[22];
    const float* act_b   = (const float*)d_in[23];

    // ---- workspace layout (~187 MB; R6's adaptive run proved ws >= 208 MB) ----
    char* p = (char*)d_ws;
    bf16* h_all  = (bf16*)p; p += (size_t)NHF * 2;
    bf16* c_all  = (bf16*)p; p += (size_t)NHF * 2;
    bf16* h3_all = (bf16*)p; p += (size_t)NHF * 2;
    bf16* BT1 = (bf16*)p; p += (size_t)T1SZ * 2;
    bf16* BT2 = (bf16*)p; p += (size_t)T2SZ * 2;
    bf16* W1T = (bf16*)p; p += (size_t)WSZ * 2;
    bf16* W2T = (bf16*)p; p += (size_t)WSZ * 2;
    bf16* WhT = (bf16*)p; p += (size_t)HSZ * 2;
    bf16* Sb  = (bf16*)p;              // bf16 S: up to 8191 x 4608 = 75.5 MB
    bf16* t1  = c_all;                 // FFN hidden aliases dead c
    bf16* h4  = h_all;                 // FFN out aliases dead h
    float* Lg = (float*)h3_all;        // head logits alias dead h3 (8.4 MB)

    // ---- weight conversions: ONE kernel ----
    conv_k<<<(CONVTOT + 255) / 256, 256, 0, stream>>>(
        Ub_iou, Ub_f, Ut_iou, Ut_f, ffn_W1, ffn_W2, hl_W, int_W, act_W,
        BT1, BT2, W1T, W2T, WhT);

    // ---- leaves (both passes, one kernel) ----
    leaf_k<<<(8192 * HD + 255) / 256, 256, 0, stream>>>(
        ids, Wb_iou, bb_iou, Wt_iou, bt_iou, h_all, c_all, h3_all);

    // ---- pass 1: split mm+cell for n>=512, fused fmm for small levels ----
    for (int d = 12; d >= 0; --d) {
        int n = 1 << d;
        if (n >= 512) {
            mm_k<3, 0><<<dim3(30, n / 128), 256, 0, stream>>>(
                h_all + (size_t)(2 * n - 1) * HD, BT1, nullptr, Sb, nullptr,
                n, 3840, 1536);
            cell1_k<<<(n * HD + 255) / 256, 256, 0, stream>>>(
                ids, Sb, Wb_iou, bb_iou, Wb_f, bb_f, h_all, c_all, n, n - 1);
        } else {
            fmm_k<<<dim3(12, (n + 63) / 64), 256, 0, stream>>>(
                ids, h_all + (size_t)(2 * n - 1) * HD, BT1,
                Wb_iou, bb_iou, Wb_f, bb_f, c_all, h_all, c_all, n, n - 1);
        }
    }

    // ---- pass 2: single chunk, gather fused into GEMM ----
    mm_k<3, 1><<<dim3(36, 64), 256, 0, stream>>>(
        h_all, BT2, nullptr, Sb, nullptr, NLEAF_OFF, 4608, 2304);
    cell2_k<<<(NLEAF_OFF * HD + 255) / 256, 256, 0, stream>>>(
        ids, Sb, Wt_iou, bt_iou, Wt_f, bt_f, c_all, h3_all, NLEAF_OFF, 0);

    // ---- FFN ----
    mm_k<1, 0><<<dim3(6, 128), 256, 0, stream>>>(
        h3_all, W1T, nullptr, t1, ffn_b1, N_NODES, 768, 768);
    mm_k<2, 0><<<dim3(6, 128), 256, 0, stream>>>(
        t1, W2T, nullptr, h4, ffn_b2, N_NODES, 768, 768);

    // ---- heads: logits GEMM + softmax ----
    mm_k<0, 0><<<dim3(1, 128), 256, 0, stream>>>(
        h4, WhT, Lg, nullptr, nullptr, N_NODES, 128, 768);
    hsm_k<<<(N_NODES + 3) / 4, 256, 0, stream>>>(
        Lg, mask, hl_b, int_b, act_b, (float*)d_out);
}